// Round 2
// baseline (315.557 us; speedup 1.0000x reference)
//
#include <hip/hip_runtime.h>

#define NIMG    4991
#define RIRLEN  3968
#define NT      256
#define BPB     16           // blocks (partials) per batch element
#define MSPLIT  4            // merge blocks per batch element
#define INV_PI  0.31830988618379067f
#define SR_OVER_C 46.647230320699704f   // 16000 / 343
// keep image iff dist^2 <= (4007/46.647)^2 ~= 7378.8 (else ti0 >= RIRLEN, all taps masked)
#define DIST2_MAX 7380.0f

// ---- compile-time compact image-source table: all (x,y,z), |x|+|y|+|z| <= 15 ----
struct Tab { int v[NIMG]; };
static constexpr Tab make_tab() {
    Tab t{};
    int k = 0;
    for (int x = -15; x <= 15; ++x)
        for (int y = -15; y <= 15; ++y)
            for (int z = -15; z <= 15; ++z) {
                int ax = x < 0 ? -x : x;
                int ay = y < 0 ? -y : y;
                int az = z < 0 ? -z : z;
                if (ax + ay + az <= 15)
                    t.v[k++] = (x + 15) | ((y + 15) << 8) | ((z + 15) << 16);
            }
    return t;
}
__constant__ Tab c_tab = make_tab();

static __device__ __forceinline__ int iabs(int v) { return v < 0 ? -v : v; }

__global__ __launch_bounds__(NT, 8)
void rir_kernel(const float* __restrict__ inp, float* __restrict__ out,
                float* __restrict__ ws, int B, int use_ws) {
    const int b     = blockIdx.x / BPB;
    const int chunk = blockIdx.x % BPB;
    const int tid   = threadIdx.x;
    const int lane  = tid & 63;
    const int sub   = lane & 7;         // tap-lane within 8-lane image group
    const int grp   = lane >> 3;        // image group 0..7 within wave
    const int wave  = tid >> 6;         // 0..3

    __shared__ float4 s_rir4[RIRLEN / 4];
    __shared__ float  s_par[12];
    __shared__ int    s_list[320];      // live-image list (<= ceil(4991/16) = 312)
    __shared__ int    s_cnt;
    float* s_rir = (float*)s_rir4;

    for (int t = tid; t < RIRLEN / 4; t += NT)
        s_rir4[t] = make_float4(0.f, 0.f, 0.f, 0.f);
    if (tid == 0) {
        s_cnt = 0;
        const float* ip = inp + b * 12;
        float rx = ip[0], ry = ip[1], rz = ip[2];
        float mx = ip[3] * rx, my = ip[4] * ry, mz = ip[5] * rz;
        float sx = ip[6] * rx, sy = ip[7] * ry, sz = ip[8] * rz;
        float aw = __builtin_fmaf(ip[9],  0.84f, 0.01f);
        float a4 = __builtin_fmaf(ip[10], 0.84f, 0.01f);
        float a5 = __builtin_fmaf(ip[11], 0.84f, 0.01f);
        s_par[0] = rx; s_par[1] = ry; s_par[2] = rz;
        s_par[3] = mx; s_par[4] = my; s_par[5] = mz;
        s_par[6] = sx; s_par[7] = sy; s_par[8] = sz;
        // log2(tr) = 0.5 * log2(1 - a)
        s_par[9]  = 0.5f * __builtin_amdgcn_logf(1.0f - aw);
        s_par[10] = 0.5f * __builtin_amdgcn_logf(1.0f - a4);
        s_par[11] = 0.5f * __builtin_amdgcn_logf(1.0f - a5);
        if (chunk == 0) {
            float dx = mx - sx, dy = my - sy, dz = mz - sz;
            out[(size_t)B * RIRLEN + b] = __builtin_fmaf(
                __builtin_sqrtf(dx * dx + dy * dy + dz * dz), SR_OVER_C, 40.0f);
        }
    }
    __syncthreads();

    const float rx = s_par[0], ry = s_par[1], rz = s_par[2];
    const float mx = s_par[3], my = s_par[4], mz = s_par[5];
    const float sx = s_par[6], sy = s_par[7], sz = s_par[8];
    const float lw = s_par[9], l4 = s_par[10], l5 = s_par[11];

    // ---- prune pass: stride-BPB interleaved candidates -> LDS live list ----
    for (int k = tid; ; k += NT) {
        const int idx = chunk + k * BPB;
        if (idx >= NIMG) break;
        const int p = c_tab.v[idx];
        const int x = (p & 255) - 15;
        const int y = ((p >> 8) & 255) - 15;
        const int z = ((p >> 16) & 255) - 15;
        const float ix = (x & 1) ? __builtin_fmaf(rx, (float)(x + 1), -sx)
                                 : __builtin_fmaf(rx, (float)x, sx);
        const float iy = (y & 1) ? __builtin_fmaf(ry, (float)(y + 1), -sy)
                                 : __builtin_fmaf(ry, (float)y, sy);
        const float iz = (z & 1) ? __builtin_fmaf(rz, (float)(z + 1), -sz)
                                 : __builtin_fmaf(rz, (float)z, sz);
        const float dx = ix - mx, dy = iy - my, dz = iz - mz;
        const float d2 = __builtin_fmaf(dx, dx, __builtin_fmaf(dy, dy, dz * dz));
        if (d2 <= DIST2_MAX) {
            const int slot = atomicAdd(&s_cnt, 1);
            s_list[slot] = p;
        }
    }
    __syncthreads();
    const int cnt = s_cnt;

    // Per-lane Hann-table constants: this lane owns taps j = sub + 8k, k=0..9.
    // cos/sin(pi*(j-40)/40) -> (j-40)/80 revolutions for v_sin/v_cos.
    float cj[10], sj[10];
    #pragma unroll
    for (int k = 0; k < 10; ++k) {
        const float rev = (float)(sub + 8 * k - 40) * (1.0f / 80.0f);
        cj[k] = __builtin_amdgcn_cosf(rev);
        sj[k] = __builtin_amdgcn_sinf(rev);
    }
    // sinc sign (-1)^j: j parity == sub parity (stride 8). Fold 1/pi in.
    const float slane = (sub & 1) ? -INV_PI : INV_PI;

    // ---- main loop: 8 images per wave per round, 8 lanes x 10 taps each ----
    for (int base = wave * 8; base < cnt; base += 32) {
        const int e = base + grp;
        const int p = s_list[e < cnt ? e : cnt - 1];   // clamp; masked via amp=0

        const int x = (p & 255) - 15;
        const int y = ((p >> 8) & 255) - 15;
        const int z = ((p >> 16) & 255) - 15;

        const float ix = (x & 1) ? __builtin_fmaf(rx, (float)(x + 1), -sx)
                                 : __builtin_fmaf(rx, (float)x, sx);
        const float iy = (y & 1) ? __builtin_fmaf(ry, (float)(y + 1), -sy)
                                 : __builtin_fmaf(ry, (float)y, sy);
        const float iz = (z & 1) ? __builtin_fmaf(rz, (float)(z + 1), -sz)
                                 : __builtin_fmaf(rz, (float)z, sz);

        const float dx = ix - mx, dy = iy - my, dz = iz - mz;
        const float dist  = __builtin_sqrtf(__builtin_fmaf(dx, dx, __builtin_fmaf(dy, dy, dz * dz)));
        const float delay = dist * SR_OVER_C;
        const float di    = __builtin_ceilf(delay);
        const int   ti0   = (int)di - 40;

        // att = prod tr^exp == exp2( sum e * log2(tr) )
        const int ew = iabs(x >> 1) + iabs((x + 1) >> 1) + iabs(y >> 1) + iabs((y + 1) >> 1);
        const float att = __builtin_amdgcn_exp2f(__builtin_fmaf((float)ew, lw,
                              __builtin_fmaf((float)iabs(z >> 1), l4,
                                   (float)iabs((z + 1) >> 1) * l5)));
        float amp = att * __builtin_amdgcn_rcpf(dist);
        if (e >= cnt) amp = 0.0f;                      // invalid lane -> adds zeros

        const float frac = di - delay;                 // in [0,1)
        // sin(pi*frac): pi*frac rad = frac/2 rev; sign + 1/pi folded via slane
        const float c1  = amp * __builtin_amdgcn_sinf(0.5f * frac) * slane;
        // hann angle pi*frac/40 rad = frac/80 rev
        const float ca  = 0.5f * __builtin_amdgcn_cosf(frac * (1.0f / 80.0f));
        const float nsa = -0.5f * __builtin_amdgcn_sinf(frac * (1.0f / 80.0f));

        const float x0 = frac + (float)(sub - 40);
        const int   t0 = ti0 + sub;
        #pragma unroll
        for (int k = 0; k < 10; ++k) {
            const float xv = x0 + (float)(8 * k);
            // hann(x) = 0.5 + ca*cos_j - sa*sin_j  (angle addition, per-lane table)
            const float h = __builtin_fmaf(ca, cj[k], __builtin_fmaf(nsa, sj[k], 0.5f));
            float v = c1 * h * __builtin_amdgcn_rcpf(xv);
            v = (xv == 0.0f) ? amp : v;                // sinc(0)*hann(0) = 1
            const int t = t0 + 8 * k;
            // 8 runs of 8 consecutive addresses -> low-conflict ds_add
            if ((unsigned)t < (unsigned)RIRLEN) atomicAdd(&s_rir[t], v);
        }
    }
    __syncthreads();

    if (use_ws) {
        // non-atomic partial dump; merged by merge_kernel
        float4* wrow = (float4*)ws + (size_t)blockIdx.x * (RIRLEN / 4);
        for (int t = tid; t < RIRLEN / 4; t += NT) wrow[t] = s_rir4[t];
    } else {
        float* orow = out + (size_t)b * RIRLEN;
        for (int t = tid; t < RIRLEN; t += NT) {
            const float v = s_rir[t];
            if (v != 0.0f) atomicAdd(&orow[t], v);
        }
    }
}

__global__ __launch_bounds__(NT)
void merge_kernel(const float* __restrict__ ws, float* __restrict__ out, int B) {
    const int b = blockIdx.x / MSPLIT;
    const int q = blockIdx.x % MSPLIT;
    const int n4   = RIRLEN / 4;        // 992
    const int span = n4 / MSPLIT;       // 248
    const float4* wb = (const float4*)ws + (size_t)b * BPB * n4;
    float4* ob = (float4*)(out + (size_t)b * RIRLEN);
    for (int t = q * span + threadIdx.x; t < (q + 1) * span; t += NT) {
        float4 a = wb[t];
        #pragma unroll
        for (int c = 1; c < BPB; ++c) {
            const float4 v = wb[(size_t)c * n4 + t];
            a.x += v.x; a.y += v.y; a.z += v.z; a.w += v.w;
        }
        ob[t] = a;
    }
}

extern "C" void kernel_launch(void* const* d_in, const int* in_sizes, int n_in,
                              void* d_out, int out_size, void* d_ws, size_t ws_size,
                              hipStream_t stream) {
    const float* inp = (const float*)d_in[0];
    float* out = (float*)d_out;
    const int B = in_sizes[0] / 12;
    const size_t need = (size_t)B * BPB * RIRLEN * sizeof(float);
    const int use_ws = (d_ws != nullptr && ws_size >= need) ? 1 : 0;
    if (!use_ws)
        (void)hipMemsetAsync(d_out, 0, (size_t)out_size * sizeof(float), stream);
    rir_kernel<<<dim3(B * BPB), dim3(NT), 0, stream>>>(inp, out, (float*)d_ws, B, use_ws);
    if (use_ws)
        merge_kernel<<<dim3(B * MSPLIT), dim3(NT), 0, stream>>>((const float*)d_ws, out, B);
}

// Round 3
// 260.278 us; speedup vs baseline: 1.2124x; 1.2124x over previous
//
#include <hip/hip_runtime.h>

#define NIMG    4991
#define RIRLEN  3968
#define NT      256
#define NB      256          // ti0 buckets: width 16, offset +64 -> bucket=(ti0+64)>>4
#define GSPLIT  16           // gather blocks per batch (4 waves each; 62 live waves)
#define NWAVES  62           // RIRLEN / 64
#define BPB     16           // fallback scatter blocks per batch
#define INV_PI  0.31830988618379067f
#define SR_OVER_C 46.647230320699704f   // 16000 / 343

// ---- compile-time compact image-source table: all (x,y,z), |x|+|y|+|z| <= 15 ----
struct Tab { int v[NIMG]; };
static constexpr Tab make_tab() {
    Tab t{};
    int k = 0;
    for (int x = -15; x <= 15; ++x)
        for (int y = -15; y <= 15; ++y)
            for (int z = -15; z <= 15; ++z) {
                int ax = x < 0 ? -x : x;
                int ay = y < 0 ? -y : y;
                int az = z < 0 ? -z : z;
                if (ax + ay + az <= 15)
                    t.v[k++] = (x + 15) | ((y + 15) << 8) | ((z + 15) << 16);
            }
    return t;
}
__constant__ Tab c_tab = make_tab();

static __device__ __forceinline__ int iabs(int v) { return v < 0 ? -v : v; }

// ============================================================================
// K1: per-batch prep. Computes per-image params, bucket-sorts by ti0 into ws.
// params layout per image (stride 8 floats): {delay, c1p, Cd, Sd, amp, -, -, -}
//   c1p = amp * (-1)^di * sin(pi*frac) / pi
//   Cd  = 0.5*cos(2*pi*((di mod 80) - frac)/80),  Sd = 0.5*sin(...)
// ============================================================================
__global__ __launch_bounds__(NT)
void rir_prep(const float* __restrict__ inp, float* __restrict__ out,
              float* __restrict__ params, int* __restrict__ offs, int B) {
    const int b   = blockIdx.x;
    const int tid = threadIdx.x;

    __shared__ float s_par[12];
    __shared__ int   s_hist[NB];
    __shared__ int   s_scan[NB];
    __shared__ int   s_off[NB + 1];

    s_hist[tid] = 0;
    if (tid == 0) {
        const float* ip = inp + b * 12;
        float rx = ip[0], ry = ip[1], rz = ip[2];
        float mx = ip[3] * rx, my = ip[4] * ry, mz = ip[5] * rz;
        float sx = ip[6] * rx, sy = ip[7] * ry, sz = ip[8] * rz;
        float aw = __builtin_fmaf(ip[9],  0.84f, 0.01f);
        float a4 = __builtin_fmaf(ip[10], 0.84f, 0.01f);
        float a5 = __builtin_fmaf(ip[11], 0.84f, 0.01f);
        s_par[0] = rx; s_par[1] = ry; s_par[2] = rz;
        s_par[3] = mx; s_par[4] = my; s_par[5] = mz;
        s_par[6] = sx; s_par[7] = sy; s_par[8] = sz;
        s_par[9]  = 0.5f * __builtin_amdgcn_logf(1.0f - aw);   // log2(tr) per axis pair
        s_par[10] = 0.5f * __builtin_amdgcn_logf(1.0f - a4);
        s_par[11] = 0.5f * __builtin_amdgcn_logf(1.0f - a5);
        float dx = mx - sx, dy = my - sy, dz = mz - sz;
        out[(size_t)B * RIRLEN + b] = __builtin_fmaf(
            __builtin_sqrtf(dx * dx + dy * dy + dz * dz), SR_OVER_C, 40.0f);
    }
    __syncthreads();

    const float rx = s_par[0], ry = s_par[1], rz = s_par[2];
    const float mx = s_par[3], my = s_par[4], mz = s_par[5];
    const float sx = s_par[6], sy = s_par[7], sz = s_par[8];
    const float lw = s_par[9], l4 = s_par[10], l5 = s_par[11];

    // ---- pass A: histogram of ti0 buckets ----
    for (int idx = tid; idx < NIMG; idx += NT) {
        const int p = c_tab.v[idx];
        const int x = (p & 255) - 15;
        const int y = ((p >> 8) & 255) - 15;
        const int z = ((p >> 16) & 255) - 15;
        const float ix = (x & 1) ? __builtin_fmaf(rx, (float)(x + 1), -sx)
                                 : __builtin_fmaf(rx, (float)x, sx);
        const float iy = (y & 1) ? __builtin_fmaf(ry, (float)(y + 1), -sy)
                                 : __builtin_fmaf(ry, (float)y, sy);
        const float iz = (z & 1) ? __builtin_fmaf(rz, (float)(z + 1), -sz)
                                 : __builtin_fmaf(rz, (float)z, sz);
        const float dx = ix - mx, dy = iy - my, dz = iz - mz;
        const float dist  = __builtin_sqrtf(__builtin_fmaf(dx, dx, __builtin_fmaf(dy, dy, dz * dz)));
        const float delay = dist * SR_OVER_C;
        const int   ti0   = (int)__builtin_ceilf(delay) - 40;
        if (ti0 < RIRLEN) atomicAdd(&s_hist[(ti0 + 64) >> 4], 1);
    }
    __syncthreads();

    // ---- exclusive scan over NB==NT buckets (Hillis-Steele) ----
    int vc = s_hist[tid];
    s_scan[tid] = vc;
    __syncthreads();
    for (int d = 1; d < NB; d <<= 1) {
        int tv = (tid >= d) ? s_scan[tid - d] : 0;
        __syncthreads();
        s_scan[tid] += tv;
        __syncthreads();
    }
    if (tid == 0) s_off[0] = 0;
    s_off[tid + 1] = s_scan[tid];
    __syncthreads();
    offs[b * (NB + 1) + tid] = s_off[tid];
    if (tid == NT - 1) offs[b * (NB + 1) + NB] = s_off[NB];
    s_hist[tid] = s_off[tid];          // reuse as per-bucket cursors
    __syncthreads();

    // ---- pass B: full params, scatter into bucket-sorted order ----
    float* pb = params + (size_t)b * NIMG * 8;
    for (int idx = tid; idx < NIMG; idx += NT) {
        const int p = c_tab.v[idx];
        const int x = (p & 255) - 15;
        const int y = ((p >> 8) & 255) - 15;
        const int z = ((p >> 16) & 255) - 15;
        const float ix = (x & 1) ? __builtin_fmaf(rx, (float)(x + 1), -sx)
                                 : __builtin_fmaf(rx, (float)x, sx);
        const float iy = (y & 1) ? __builtin_fmaf(ry, (float)(y + 1), -sy)
                                 : __builtin_fmaf(ry, (float)y, sy);
        const float iz = (z & 1) ? __builtin_fmaf(rz, (float)(z + 1), -sz)
                                 : __builtin_fmaf(rz, (float)z, sz);
        const float dx = ix - mx, dy = iy - my, dz = iz - mz;
        const float dist  = __builtin_sqrtf(__builtin_fmaf(dx, dx, __builtin_fmaf(dy, dy, dz * dz)));
        const float delay = dist * SR_OVER_C;
        const float di    = __builtin_ceilf(delay);
        const int   ti0   = (int)di - 40;
        if (ti0 >= RIRLEN) continue;

        const int ew = iabs(x >> 1) + iabs((x + 1) >> 1) + iabs(y >> 1) + iabs((y + 1) >> 1);
        const float att = __builtin_amdgcn_exp2f(__builtin_fmaf((float)ew, lw,
                              __builtin_fmaf((float)iabs(z >> 1), l4,
                                   (float)iabs((z + 1) >> 1) * l5)));
        const float amp  = att * __builtin_amdgcn_rcpf(dist);
        const float frac = di - delay;                 // in [0,1), exact (Sterbenz)
        const int   dii  = (int)di;
        float c1p = amp * __builtin_amdgcn_sinf(0.5f * frac) * INV_PI;  // sin(pi*frac)
        if (dii & 1) c1p = -c1p;
        const int   md   = dii - (dii / 80) * 80;       // di mod 80 (exact)
        const float revd = ((float)md - frac) * 0.0125f; // (md - frac)/80 revolutions
        const float Cd   = 0.5f * __builtin_amdgcn_cosf(revd);
        const float Sd   = 0.5f * __builtin_amdgcn_sinf(revd);

        const int slot = atomicAdd(&s_hist[(ti0 + 64) >> 4], 1);
        float4* q = (float4*)(pb + (size_t)slot * 8);
        q[0] = make_float4(delay, c1p, Cd, Sd);
        q[1] = make_float4(amp, 0.0f, 0.0f, 0.0f);
    }
}

// ============================================================================
// K2: gather. One wave owns 64 consecutive output bins; loops over only the
// images whose 81-tap window can overlap (bucket range), accumulating in a
// register. No LDS, no atomics; image params are wave-uniform broadcast loads.
//   v(t) = (-1)^t * c1p * rcp(t - delay) * (0.5 + cos_t*Cd + sin_t*Sd)
// with the per-lane sign folded into the per-lane hann constants.
// ============================================================================
__global__ __launch_bounds__(NT)
void rir_gather(const float* __restrict__ params, const int* __restrict__ offs,
                float* __restrict__ out, int B) {
    const int b    = blockIdx.x >> 4;
    const int rblk = blockIdx.x & (GSPLIT - 1);
    const int wv   = rblk * 4 + (threadIdx.x >> 6);
    if (wv >= NWAVES) return;
    const int lane = threadIdx.x & 63;
    const int t    = wv * 64 + lane;
    const float tf = (float)t;

    // per-lane hann constants with (-1)^t folded in
    const int   m   = t - (t / 80) * 80;                 // t mod 80
    const float sl  = (t & 1) ? -1.0f : 1.0f;
    const float rev = (float)m * 0.0125f;                // m/80 revolutions
    const float cth = sl * __builtin_amdgcn_cosf(rev);
    const float sth = sl * __builtin_amdgcn_sinf(rev);
    const float hh  = sl * 0.5f;

    // bucket range covering ti0 in [T0-80, T0+63]
    int bmin = (wv * 64 - 16) >> 4;                      // (T0-80+64)>>4
    if (bmin < 0) bmin = 0;
    int bmax = (wv * 64 + 127) >> 4;                     // (T0+63+64)>>4
    if (bmax > NB - 1) bmax = NB - 1;
    const int* ob = offs + b * (NB + 1);
    const int lo = ob[bmin];
    const int hi = ob[bmax + 1];

    const float4* pp = (const float4*)(params + (size_t)b * NIMG * 8);
    float acc = 0.0f;

    float4 Pa, Pb;
    if (lo < hi) { Pa = pp[2 * lo]; Pb = pp[2 * lo + 1]; }
    for (int i = lo; i < hi; ++i) {
        const float4 Ca = Pa;
        const float4 Cb = Pb;
        if (i + 1 < hi) { Pa = pp[2 * i + 2]; Pb = pp[2 * i + 3]; }  // prefetch

        const float x = tf - Ca.x;                       // t - delay
        const float h = __builtin_fmaf(cth, Ca.z, __builtin_fmaf(sth, Ca.w, hh));
        float v = Ca.y * h * __builtin_amdgcn_rcpf(x);
        v = (x == 0.0f) ? Cb.x : v;                      // sinc(0)*hann(0)=1 -> amp
        v = (__builtin_fabsf(x) <= 40.0f) ? v : 0.0f;    // window mask (j in [0,80])
        acc += v;
    }
    out[(size_t)b * RIRLEN + t] = acc;
}

// ============================================================================
// Fallback (ws too small): round-2 scatter kernel with global-atomic epilogue.
// ============================================================================
__global__ __launch_bounds__(NT, 8)
void rir_scatter(const float* __restrict__ inp, float* __restrict__ out, int B) {
    const int b     = blockIdx.x / BPB;
    const int chunk = blockIdx.x % BPB;
    const int tid   = threadIdx.x;
    const int lane  = tid & 63;
    const int sub   = lane & 7;
    const int grp   = lane >> 3;
    const int wave  = tid >> 6;

    __shared__ float s_rir[RIRLEN];
    __shared__ float s_par[12];
    __shared__ int   s_list[320];
    __shared__ int   s_cnt;

    for (int t = tid; t < RIRLEN; t += NT) s_rir[t] = 0.0f;
    if (tid == 0) {
        s_cnt = 0;
        const float* ip = inp + b * 12;
        float rx = ip[0], ry = ip[1], rz = ip[2];
        float mx = ip[3] * rx, my = ip[4] * ry, mz = ip[5] * rz;
        float sx = ip[6] * rx, sy = ip[7] * ry, sz = ip[8] * rz;
        float aw = __builtin_fmaf(ip[9],  0.84f, 0.01f);
        float a4 = __builtin_fmaf(ip[10], 0.84f, 0.01f);
        float a5 = __builtin_fmaf(ip[11], 0.84f, 0.01f);
        s_par[0] = rx; s_par[1] = ry; s_par[2] = rz;
        s_par[3] = mx; s_par[4] = my; s_par[5] = mz;
        s_par[6] = sx; s_par[7] = sy; s_par[8] = sz;
        s_par[9]  = 0.5f * __builtin_amdgcn_logf(1.0f - aw);
        s_par[10] = 0.5f * __builtin_amdgcn_logf(1.0f - a4);
        s_par[11] = 0.5f * __builtin_amdgcn_logf(1.0f - a5);
        if (chunk == 0) {
            float dx = mx - sx, dy = my - sy, dz = mz - sz;
            out[(size_t)B * RIRLEN + b] = __builtin_fmaf(
                __builtin_sqrtf(dx * dx + dy * dy + dz * dz), SR_OVER_C, 40.0f);
        }
    }
    __syncthreads();

    const float rx = s_par[0], ry = s_par[1], rz = s_par[2];
    const float mx = s_par[3], my = s_par[4], mz = s_par[5];
    const float sx = s_par[6], sy = s_par[7], sz = s_par[8];
    const float lw = s_par[9], l4 = s_par[10], l5 = s_par[11];

    for (int k = tid; ; k += NT) {
        const int idx = chunk + k * BPB;
        if (idx >= NIMG) break;
        const int p = c_tab.v[idx];
        const int x = (p & 255) - 15;
        const int y = ((p >> 8) & 255) - 15;
        const int z = ((p >> 16) & 255) - 15;
        const float ix = (x & 1) ? __builtin_fmaf(rx, (float)(x + 1), -sx)
                                 : __builtin_fmaf(rx, (float)x, sx);
        const float iy = (y & 1) ? __builtin_fmaf(ry, (float)(y + 1), -sy)
                                 : __builtin_fmaf(ry, (float)y, sy);
        const float iz = (z & 1) ? __builtin_fmaf(rz, (float)(z + 1), -sz)
                                 : __builtin_fmaf(rz, (float)z, sz);
        const float dx = ix - mx, dy = iy - my, dz = iz - mz;
        const float d2 = __builtin_fmaf(dx, dx, __builtin_fmaf(dy, dy, dz * dz));
        if (d2 <= 7380.0f) {
            const int slot = atomicAdd(&s_cnt, 1);
            s_list[slot] = p;
        }
    }
    __syncthreads();
    const int cnt = s_cnt;

    float cj[10], sj[10];
    #pragma unroll
    for (int k = 0; k < 10; ++k) {
        const float rev = (float)(sub + 8 * k - 40) * (1.0f / 80.0f);
        cj[k] = __builtin_amdgcn_cosf(rev);
        sj[k] = __builtin_amdgcn_sinf(rev);
    }
    const float slane = (sub & 1) ? -INV_PI : INV_PI;

    for (int base = wave * 8; base < cnt; base += 32) {
        const int e = base + grp;
        const int p = s_list[e < cnt ? e : cnt - 1];
        const int x = (p & 255) - 15;
        const int y = ((p >> 8) & 255) - 15;
        const int z = ((p >> 16) & 255) - 15;
        const float ix = (x & 1) ? __builtin_fmaf(rx, (float)(x + 1), -sx)
                                 : __builtin_fmaf(rx, (float)x, sx);
        const float iy = (y & 1) ? __builtin_fmaf(ry, (float)(y + 1), -sy)
                                 : __builtin_fmaf(ry, (float)y, sy);
        const float iz = (z & 1) ? __builtin_fmaf(rz, (float)(z + 1), -sz)
                                 : __builtin_fmaf(rz, (float)z, sz);
        const float dx = ix - mx, dy = iy - my, dz = iz - mz;
        const float dist  = __builtin_sqrtf(__builtin_fmaf(dx, dx, __builtin_fmaf(dy, dy, dz * dz)));
        const float delay = dist * SR_OVER_C;
        const float di    = __builtin_ceilf(delay);
        const int   ti0   = (int)di - 40;
        const int ew = iabs(x >> 1) + iabs((x + 1) >> 1) + iabs(y >> 1) + iabs((y + 1) >> 1);
        const float att = __builtin_amdgcn_exp2f(__builtin_fmaf((float)ew, lw,
                              __builtin_fmaf((float)iabs(z >> 1), l4,
                                   (float)iabs((z + 1) >> 1) * l5)));
        float amp = att * __builtin_amdgcn_rcpf(dist);
        if (e >= cnt) amp = 0.0f;
        const float frac = di - delay;
        const float c1  = amp * __builtin_amdgcn_sinf(0.5f * frac) * slane;
        const float ca  = 0.5f * __builtin_amdgcn_cosf(frac * (1.0f / 80.0f));
        const float nsa = -0.5f * __builtin_amdgcn_sinf(frac * (1.0f / 80.0f));
        const float x0 = frac + (float)(sub - 40);
        const int   t0 = ti0 + sub;
        #pragma unroll
        for (int k = 0; k < 10; ++k) {
            const float xv = x0 + (float)(8 * k);
            const float h = __builtin_fmaf(ca, cj[k], __builtin_fmaf(nsa, sj[k], 0.5f));
            float v = c1 * h * __builtin_amdgcn_rcpf(xv);
            v = (xv == 0.0f) ? amp : v;
            const int t = t0 + 8 * k;
            if ((unsigned)t < (unsigned)RIRLEN) atomicAdd(&s_rir[t], v);
        }
    }
    __syncthreads();

    float* orow = out + (size_t)b * RIRLEN;
    for (int t = tid; t < RIRLEN; t += NT) {
        const float v = s_rir[t];
        if (v != 0.0f) atomicAdd(&orow[t], v);
    }
}

extern "C" void kernel_launch(void* const* d_in, const int* in_sizes, int n_in,
                              void* d_out, int out_size, void* d_ws, size_t ws_size,
                              hipStream_t stream) {
    const float* inp = (const float*)d_in[0];
    float* out = (float*)d_out;
    const int B = in_sizes[0] / 12;

    const size_t params_bytes = (size_t)B * NIMG * 8 * sizeof(float);
    const size_t offs_bytes   = (size_t)B * (NB + 1) * sizeof(int);
    const int use_ws = (d_ws != nullptr && ws_size >= params_bytes + offs_bytes) ? 1 : 0;

    if (use_ws) {
        float* params = (float*)d_ws;
        int*   offs   = (int*)((char*)d_ws + params_bytes);
        rir_prep  <<<dim3(B),          dim3(NT), 0, stream>>>(inp, out, params, offs, B);
        rir_gather<<<dim3(B * GSPLIT), dim3(NT), 0, stream>>>(params, offs, out, B);
    } else {
        (void)hipMemsetAsync(d_out, 0, (size_t)out_size * sizeof(float), stream);
        rir_scatter<<<dim3(B * BPB), dim3(NT), 0, stream>>>(inp, out, B);
    }
}

// Round 4
// 219.448 us; speedup vs baseline: 1.4380x; 1.1861x over previous
//
#include <hip/hip_runtime.h>

#define NIMG    4991
#define NIMG_P  4999         // NIMG + 8 zero-pad entries (chunked over-read safety)
#define RIRLEN  3968
#define NT      256
#define NB      256          // ti0 buckets: width 16, offset +64 -> bucket=(ti0+64)>>4
#define GT      128          // gather block = 2 waves
#define GBPB    31           // gather blocks per batch (31*2 = 62 waves = RIRLEN/64)
#define BPB     16           // fallback scatter blocks per batch
#define INV_PI  0.31830988618379067f
#define SR_OVER_C 46.647230320699704f   // 16000 / 343

// ---- compile-time compact image-source table: all (x,y,z), |x|+|y|+|z| <= 15 ----
struct Tab { int v[NIMG]; };
static constexpr Tab make_tab() {
    Tab t{};
    int k = 0;
    for (int x = -15; x <= 15; ++x)
        for (int y = -15; y <= 15; ++y)
            for (int z = -15; z <= 15; ++z) {
                int ax = x < 0 ? -x : x;
                int ay = y < 0 ? -y : y;
                int az = z < 0 ? -z : z;
                if (ax + ay + az <= 15)
                    t.v[k++] = (x + 15) | ((y + 15) << 8) | ((z + 15) << 16);
            }
    return t;
}
__constant__ Tab c_tab = make_tab();

static __device__ __forceinline__ int iabs(int v) { return v < 0 ? -v : v; }

// ============================================================================
// K1: per-batch prep. Per-image params, bucket-sorted by ti0 into ws.
// Entry (8 floats): {delay, Hp, Cdp, Sdp} {amp, 0, 0, 0}
//   c1p = amp * (-1)^di * sin(pi*frac) / pi        (frac = ceil(delay)-delay)
//   Hp  = 0.5*c1p
//   Cdp = 0.5*c1p*cos(2*pi*(di mod 80 - frac)/80), Sdp = 0.5*c1p*sin(...)
// Gather evaluates v(t) = (-1)^t * (Hp + cos_t*Cdp + sin_t*Sdp) / (t - delay).
// 8 zero entries are appended so the gather can over-read chunk tails.
// ============================================================================
__global__ __launch_bounds__(NT)
void rir_prep(const float* __restrict__ inp, float* __restrict__ out,
              float* __restrict__ params, int* __restrict__ offs, int B) {
    const int b   = blockIdx.x;
    const int tid = threadIdx.x;

    __shared__ float s_par[12];
    __shared__ int   s_hist[NB];
    __shared__ int   s_scan[NB];
    __shared__ int   s_off[NB + 1];

    s_hist[tid] = 0;
    if (tid == 0) {
        const float* ip = inp + b * 12;
        float rx = ip[0], ry = ip[1], rz = ip[2];
        float mx = ip[3] * rx, my = ip[4] * ry, mz = ip[5] * rz;
        float sx = ip[6] * rx, sy = ip[7] * ry, sz = ip[8] * rz;
        float aw = __builtin_fmaf(ip[9],  0.84f, 0.01f);
        float a4 = __builtin_fmaf(ip[10], 0.84f, 0.01f);
        float a5 = __builtin_fmaf(ip[11], 0.84f, 0.01f);
        s_par[0] = rx; s_par[1] = ry; s_par[2] = rz;
        s_par[3] = mx; s_par[4] = my; s_par[5] = mz;
        s_par[6] = sx; s_par[7] = sy; s_par[8] = sz;
        s_par[9]  = 0.5f * __builtin_amdgcn_logf(1.0f - aw);   // log2(tr)
        s_par[10] = 0.5f * __builtin_amdgcn_logf(1.0f - a4);
        s_par[11] = 0.5f * __builtin_amdgcn_logf(1.0f - a5);
        float dx = mx - sx, dy = my - sy, dz = mz - sz;
        out[(size_t)B * RIRLEN + b] = __builtin_fmaf(
            __builtin_sqrtf(dx * dx + dy * dy + dz * dz), SR_OVER_C, 40.0f);
    }
    __syncthreads();

    const float rx = s_par[0], ry = s_par[1], rz = s_par[2];
    const float mx = s_par[3], my = s_par[4], mz = s_par[5];
    const float sx = s_par[6], sy = s_par[7], sz = s_par[8];
    const float lw = s_par[9], l4 = s_par[10], l5 = s_par[11];

    // ---- pass A: histogram of ti0 buckets ----
    for (int idx = tid; idx < NIMG; idx += NT) {
        const int p = c_tab.v[idx];
        const int x = (p & 255) - 15;
        const int y = ((p >> 8) & 255) - 15;
        const int z = ((p >> 16) & 255) - 15;
        const float ix = (x & 1) ? __builtin_fmaf(rx, (float)(x + 1), -sx)
                                 : __builtin_fmaf(rx, (float)x, sx);
        const float iy = (y & 1) ? __builtin_fmaf(ry, (float)(y + 1), -sy)
                                 : __builtin_fmaf(ry, (float)y, sy);
        const float iz = (z & 1) ? __builtin_fmaf(rz, (float)(z + 1), -sz)
                                 : __builtin_fmaf(rz, (float)z, sz);
        const float dx = ix - mx, dy = iy - my, dz = iz - mz;
        const float dist  = __builtin_sqrtf(__builtin_fmaf(dx, dx, __builtin_fmaf(dy, dy, dz * dz)));
        const float delay = dist * SR_OVER_C;
        const int   ti0   = (int)__builtin_ceilf(delay) - 40;
        if (ti0 < RIRLEN) atomicAdd(&s_hist[(ti0 + 64) >> 4], 1);
    }
    __syncthreads();

    // ---- exclusive scan over NB==NT buckets (Hillis-Steele) ----
    s_scan[tid] = s_hist[tid];
    __syncthreads();
    for (int d = 1; d < NB; d <<= 1) {
        int tv = (tid >= d) ? s_scan[tid - d] : 0;
        __syncthreads();
        s_scan[tid] += tv;
        __syncthreads();
    }
    if (tid == 0) s_off[0] = 0;
    s_off[tid + 1] = s_scan[tid];
    __syncthreads();
    offs[b * (NB + 1) + tid] = s_off[tid];
    if (tid == NT - 1) offs[b * (NB + 1) + NB] = s_off[NB];
    s_hist[tid] = s_off[tid];          // reuse as per-bucket cursors
    __syncthreads();

    float* pb = params + (size_t)b * NIMG_P * 8;

    // zero-pad 8 entries after the live list (16 float4 stores)
    {
        const int total = s_off[NB];
        if (tid < 16)
            ((float4*)(pb + (size_t)total * 8))[tid] = make_float4(0.f, 0.f, 0.f, 0.f);
    }

    // ---- pass B: full params, scattered into bucket-sorted order ----
    for (int idx = tid; idx < NIMG; idx += NT) {
        const int p = c_tab.v[idx];
        const int x = (p & 255) - 15;
        const int y = ((p >> 8) & 255) - 15;
        const int z = ((p >> 16) & 255) - 15;
        const float ix = (x & 1) ? __builtin_fmaf(rx, (float)(x + 1), -sx)
                                 : __builtin_fmaf(rx, (float)x, sx);
        const float iy = (y & 1) ? __builtin_fmaf(ry, (float)(y + 1), -sy)
                                 : __builtin_fmaf(ry, (float)y, sy);
        const float iz = (z & 1) ? __builtin_fmaf(rz, (float)(z + 1), -sz)
                                 : __builtin_fmaf(rz, (float)z, sz);
        const float dx = ix - mx, dy = iy - my, dz = iz - mz;
        const float dist  = __builtin_sqrtf(__builtin_fmaf(dx, dx, __builtin_fmaf(dy, dy, dz * dz)));
        const float delay = dist * SR_OVER_C;
        const float di    = __builtin_ceilf(delay);
        const int   ti0   = (int)di - 40;
        if (ti0 >= RIRLEN) continue;

        const int ew = iabs(x >> 1) + iabs((x + 1) >> 1) + iabs(y >> 1) + iabs((y + 1) >> 1);
        const float att = __builtin_amdgcn_exp2f(__builtin_fmaf((float)ew, lw,
                              __builtin_fmaf((float)iabs(z >> 1), l4,
                                   (float)iabs((z + 1) >> 1) * l5)));
        const float amp  = att * __builtin_amdgcn_rcpf(dist);
        const float frac = di - delay;                  // in [0,1), exact
        const int   dii  = (int)di;
        float c1p = amp * __builtin_amdgcn_sinf(0.5f * frac) * INV_PI;  // sin(pi*frac)/pi
        if (dii & 1) c1p = -c1p;
        const int   md   = dii - (dii / 80) * 80;        // di mod 80
        const float revd = ((float)md - frac) * 0.0125f; // revolutions
        const float Hp   = 0.5f * c1p;
        const float Cdp  = Hp * __builtin_amdgcn_cosf(revd);
        const float Sdp  = Hp * __builtin_amdgcn_sinf(revd);

        const int slot = atomicAdd(&s_hist[(ti0 + 64) >> 4], 1);
        float4* q = (float4*)(pb + (size_t)slot * 8);
        q[0] = make_float4(delay, Hp, Cdp, Sdp);
        q[1] = make_float4(amp, 0.0f, 0.0f, 0.0f);
    }
}

// ============================================================================
// K2: gather. 2-wave blocks; each wave owns 64 consecutive output bins and
// loops over bucket-range images in chunks of 4 (8 independent broadcast
// float4 loads -> 4x MLP). Over-read chunk tails are killed by the |x|<=40
// mask (sorted neighbors are strictly out of window) or are zero-pad.
// ============================================================================
__global__ __launch_bounds__(GT)
void rir_gather(const float* __restrict__ params, const int* __restrict__ offs,
                float* __restrict__ out, int B) {
    const int blk  = blockIdx.x;
    const int b    = blk / GBPB;
    const int wv   = (blk - b * GBPB) * 2 + (threadIdx.x >> 6);   // 0..61
    const int lane = threadIdx.x & 63;
    const int t    = wv * 64 + lane;
    const float tf = (float)t;

    // per-lane window constants (sign applied at the end)
    const int      m     = t - (t / 80) * 80;            // t mod 80
    const float    cth0  = __builtin_amdgcn_cosf((float)m * 0.0125f);
    const float    sth0  = __builtin_amdgcn_sinf((float)m * 0.0125f);
    const float    sl    = (t & 1) ? -1.0f : 1.0f;
    const unsigned smask = (unsigned)(t & 1) << 31;      // xor-sign for the x==0 amp

    // exact bucket range covering ti0 in [T0-80, T0+63]
    int bmin = (wv * 64 - 16) >> 4;  if (bmin < 0) bmin = 0;
    int bmax = (wv * 64 + 127) >> 4; if (bmax > NB - 1) bmax = NB - 1;
    const int* ob = offs + b * (NB + 1);
    const int lo = ob[bmin];
    const int hi = ob[bmax + 1];

    const float4* pp = (const float4*)(params + (size_t)b * NIMG_P * 8);
    float acc = 0.0f;

#define EVAL(A, Bq) do {                                                     \
        const float xw = tf - (A).x;                                         \
        const float hp = __builtin_fmaf(cth0, (A).z,                         \
                           __builtin_fmaf(sth0, (A).w, (A).y));              \
        float v = hp * __builtin_amdgcn_rcpf(xw);                            \
        v = (xw == 0.0f)                                                     \
              ? __uint_as_float(__float_as_uint((Bq).x) ^ smask) : v;        \
        v = (__builtin_fabsf(xw) <= 40.0f) ? v : 0.0f;                       \
        acc += v;                                                            \
    } while (0)

    for (int i = lo; i < hi; i += 4) {
        const float4* q = pp + 2 * i;
        // 8 independent broadcast loads issued before any use
        const float4 a0 = q[0], b0 = q[1];
        const float4 a1 = q[2], b1 = q[3];
        const float4 a2 = q[4], b2 = q[5];
        const float4 a3 = q[6], b3 = q[7];
        EVAL(a0, b0); EVAL(a1, b1); EVAL(a2, b2); EVAL(a3, b3);
    }
#undef EVAL

    out[(size_t)b * RIRLEN + t] = sl * acc;
}

// ============================================================================
// Fallback (ws too small): round-2 scatter kernel with global-atomic epilogue.
// ============================================================================
__global__ __launch_bounds__(NT, 8)
void rir_scatter(const float* __restrict__ inp, float* __restrict__ out, int B) {
    const int b     = blockIdx.x / BPB;
    const int chunk = blockIdx.x % BPB;
    const int tid   = threadIdx.x;
    const int lane  = tid & 63;
    const int sub   = lane & 7;
    const int grp   = lane >> 3;
    const int wave  = tid >> 6;

    __shared__ float s_rir[RIRLEN];
    __shared__ float s_par[12];
    __shared__ int   s_list[320];
    __shared__ int   s_cnt;

    for (int t = tid; t < RIRLEN; t += NT) s_rir[t] = 0.0f;
    if (tid == 0) {
        s_cnt = 0;
        const float* ip = inp + b * 12;
        float rx = ip[0], ry = ip[1], rz = ip[2];
        float mx = ip[3] * rx, my = ip[4] * ry, mz = ip[5] * rz;
        float sx = ip[6] * rx, sy = ip[7] * ry, sz = ip[8] * rz;
        float aw = __builtin_fmaf(ip[9],  0.84f, 0.01f);
        float a4 = __builtin_fmaf(ip[10], 0.84f, 0.01f);
        float a5 = __builtin_fmaf(ip[11], 0.84f, 0.01f);
        s_par[0] = rx; s_par[1] = ry; s_par[2] = rz;
        s_par[3] = mx; s_par[4] = my; s_par[5] = mz;
        s_par[6] = sx; s_par[7] = sy; s_par[8] = sz;
        s_par[9]  = 0.5f * __builtin_amdgcn_logf(1.0f - aw);
        s_par[10] = 0.5f * __builtin_amdgcn_logf(1.0f - a4);
        s_par[11] = 0.5f * __builtin_amdgcn_logf(1.0f - a5);
        if (chunk == 0) {
            float dx = mx - sx, dy = my - sy, dz = mz - sz;
            out[(size_t)B * RIRLEN + b] = __builtin_fmaf(
                __builtin_sqrtf(dx * dx + dy * dy + dz * dz), SR_OVER_C, 40.0f);
        }
    }
    __syncthreads();

    const float rx = s_par[0], ry = s_par[1], rz = s_par[2];
    const float mx = s_par[3], my = s_par[4], mz = s_par[5];
    const float sx = s_par[6], sy = s_par[7], sz = s_par[8];
    const float lw = s_par[9], l4 = s_par[10], l5 = s_par[11];

    for (int k = tid; ; k += NT) {
        const int idx = chunk + k * BPB;
        if (idx >= NIMG) break;
        const int p = c_tab.v[idx];
        const int x = (p & 255) - 15;
        const int y = ((p >> 8) & 255) - 15;
        const int z = ((p >> 16) & 255) - 15;
        const float ix = (x & 1) ? __builtin_fmaf(rx, (float)(x + 1), -sx)
                                 : __builtin_fmaf(rx, (float)x, sx);
        const float iy = (y & 1) ? __builtin_fmaf(ry, (float)(y + 1), -sy)
                                 : __builtin_fmaf(ry, (float)y, sy);
        const float iz = (z & 1) ? __builtin_fmaf(rz, (float)(z + 1), -sz)
                                 : __builtin_fmaf(rz, (float)z, sz);
        const float dx = ix - mx, dy = iy - my, dz = iz - mz;
        const float d2 = __builtin_fmaf(dx, dx, __builtin_fmaf(dy, dy, dz * dz));
        if (d2 <= 7380.0f) {
            const int slot = atomicAdd(&s_cnt, 1);
            s_list[slot] = p;
        }
    }
    __syncthreads();
    const int cnt = s_cnt;

    float cj[10], sj[10];
    #pragma unroll
    for (int k = 0; k < 10; ++k) {
        const float rev = (float)(sub + 8 * k - 40) * (1.0f / 80.0f);
        cj[k] = __builtin_amdgcn_cosf(rev);
        sj[k] = __builtin_amdgcn_sinf(rev);
    }
    const float slane = (sub & 1) ? -INV_PI : INV_PI;

    for (int base = wave * 8; base < cnt; base += 32) {
        const int e = base + grp;
        const int p = s_list[e < cnt ? e : cnt - 1];
        const int x = (p & 255) - 15;
        const int y = ((p >> 8) & 255) - 15;
        const int z = ((p >> 16) & 255) - 15;
        const float ix = (x & 1) ? __builtin_fmaf(rx, (float)(x + 1), -sx)
                                 : __builtin_fmaf(rx, (float)x, sx);
        const float iy = (y & 1) ? __builtin_fmaf(ry, (float)(y + 1), -sy)
                                 : __builtin_fmaf(ry, (float)y, sy);
        const float iz = (z & 1) ? __builtin_fmaf(rz, (float)(z + 1), -sz)
                                 : __builtin_fmaf(rz, (float)z, sz);
        const float dx = ix - mx, dy = iy - my, dz = iz - mz;
        const float dist  = __builtin_sqrtf(__builtin_fmaf(dx, dx, __builtin_fmaf(dy, dy, dz * dz)));
        const float delay = dist * SR_OVER_C;
        const float di    = __builtin_ceilf(delay);
        const int   ti0   = (int)di - 40;
        const int ew = iabs(x >> 1) + iabs((x + 1) >> 1) + iabs(y >> 1) + iabs((y + 1) >> 1);
        const float att = __builtin_amdgcn_exp2f(__builtin_fmaf((float)ew, lw,
                              __builtin_fmaf((float)iabs(z >> 1), l4,
                                   (float)iabs((z + 1) >> 1) * l5)));
        float amp = att * __builtin_amdgcn_rcpf(dist);
        if (e >= cnt) amp = 0.0f;
        const float frac = di - delay;
        const float c1  = amp * __builtin_amdgcn_sinf(0.5f * frac) * slane;
        const float ca  = 0.5f * __builtin_amdgcn_cosf(frac * (1.0f / 80.0f));
        const float nsa = -0.5f * __builtin_amdgcn_sinf(frac * (1.0f / 80.0f));
        const float x0 = frac + (float)(sub - 40);
        const int   t0 = ti0 + sub;
        #pragma unroll
        for (int k = 0; k < 10; ++k) {
            const float xv = x0 + (float)(8 * k);
            const float h = __builtin_fmaf(ca, cj[k], __builtin_fmaf(nsa, sj[k], 0.5f));
            float v = c1 * h * __builtin_amdgcn_rcpf(xv);
            v = (xv == 0.0f) ? amp : v;
            const int t = t0 + 8 * k;
            if ((unsigned)t < (unsigned)RIRLEN) atomicAdd(&s_rir[t], v);
        }
    }
    __syncthreads();

    float* orow = out + (size_t)b * RIRLEN;
    for (int t = tid; t < RIRLEN; t += NT) {
        const float v = s_rir[t];
        if (v != 0.0f) atomicAdd(&orow[t], v);
    }
}

extern "C" void kernel_launch(void* const* d_in, const int* in_sizes, int n_in,
                              void* d_out, int out_size, void* d_ws, size_t ws_size,
                              hipStream_t stream) {
    const float* inp = (const float*)d_in[0];
    float* out = (float*)d_out;
    const int B = in_sizes[0] / 12;

    const size_t params_bytes = (size_t)B * NIMG_P * 8 * sizeof(float);
    const size_t offs_bytes   = (size_t)B * (NB + 1) * sizeof(int);
    const int use_ws = (d_ws != nullptr && ws_size >= params_bytes + offs_bytes) ? 1 : 0;

    if (use_ws) {
        float* params = (float*)d_ws;
        int*   offs   = (int*)((char*)d_ws + params_bytes);
        rir_prep  <<<dim3(B),        dim3(NT), 0, stream>>>(inp, out, params, offs, B);
        rir_gather<<<dim3(B * GBPB), dim3(GT), 0, stream>>>(params, offs, out, B);
    } else {
        (void)hipMemsetAsync(d_out, 0, (size_t)out_size * sizeof(float), stream);
        rir_scatter<<<dim3(B * BPB), dim3(NT), 0, stream>>>(inp, out, B);
    }
}

// Round 5
// 129.444 us; speedup vs baseline: 2.4378x; 1.6953x over previous
//
#include <hip/hip_runtime.h>

#define NIMG    4991
#define RIRLEN  3968
#define NT      256
#define NB      256          // ti0 buckets: width 16, offset +64 -> bucket=(ti0+64)>>4
#define NWV     62           // output windows of 64 bins (RIRLEN/64)
#define SPLIT   4            // image-range quarters per window
#define GW      2048         // gather grid: 2048 blocks x 4 waves = 8192 waves
#define BPB     16           // fallback scatter blocks per batch
#define INV_PI  0.31830988618379067f
#define SR_OVER_C 46.647230320699704f   // 16000 / 343

// ---- compile-time compact image-source table: all (x,y,z), |x|+|y|+|z| <= 15 ----
struct Tab { int v[NIMG]; };
static constexpr Tab make_tab() {
    Tab t{};
    int k = 0;
    for (int x = -15; x <= 15; ++x)
        for (int y = -15; y <= 15; ++y)
            for (int z = -15; z <= 15; ++z) {
                int ax = x < 0 ? -x : x;
                int ay = y < 0 ? -y : y;
                int az = z < 0 ? -z : z;
                if (ax + ay + az <= 15)
                    t.v[k++] = (x + 15) | ((y + 15) << 8) | ((z + 15) << 16);
            }
    return t;
}
__constant__ Tab c_tab = make_tab();

static __device__ __forceinline__ int iabs(int v) { return v < 0 ? -v : v; }

// ============================================================================
// K1: per-batch prep. One float4 per image, bucket-sorted by ti0 into ws:
//   {delay, Hp, Cdp, Sdp}
//   c1p = amp * (-1)^di * sin(pi*frac) / pi        (frac = ceil(delay)-delay)
//   Hp  = 0.5*c1p
//   Cdp = 0.5*c1p*cos(2*pi*(di mod 80 - frac)/80), Sdp = 0.5*c1p*sin(...)
// Gather: v(t) = (-1)^t * (Hp + cos_t*Cdp + sin_t*Sdp) / (t - delay).
// frac==0 (exact-integer delay => c1p==0, true value = amp at t=di only) is
// special-cased: direct atomic add into out, inert entry (delay=1e9 -> masked).
// ============================================================================
__global__ __launch_bounds__(NT)
void rir_prep(const float* __restrict__ inp, float* __restrict__ out,
              float* __restrict__ params, int* __restrict__ offs, int B) {
    const int b   = blockIdx.x;
    const int tid = threadIdx.x;

    __shared__ float s_par[12];
    __shared__ int   s_hist[NB];
    __shared__ int   s_scan[NB];
    __shared__ int   s_off[NB + 1];

    s_hist[tid] = 0;
    if (tid == 0) {
        const float* ip = inp + b * 12;
        float rx = ip[0], ry = ip[1], rz = ip[2];
        float mx = ip[3] * rx, my = ip[4] * ry, mz = ip[5] * rz;
        float sx = ip[6] * rx, sy = ip[7] * ry, sz = ip[8] * rz;
        float aw = __builtin_fmaf(ip[9],  0.84f, 0.01f);
        float a4 = __builtin_fmaf(ip[10], 0.84f, 0.01f);
        float a5 = __builtin_fmaf(ip[11], 0.84f, 0.01f);
        s_par[0] = rx; s_par[1] = ry; s_par[2] = rz;
        s_par[3] = mx; s_par[4] = my; s_par[5] = mz;
        s_par[6] = sx; s_par[7] = sy; s_par[8] = sz;
        s_par[9]  = 0.5f * __builtin_amdgcn_logf(1.0f - aw);   // log2(tr)
        s_par[10] = 0.5f * __builtin_amdgcn_logf(1.0f - a4);
        s_par[11] = 0.5f * __builtin_amdgcn_logf(1.0f - a5);
        float dx = mx - sx, dy = my - sy, dz = mz - sz;
        out[(size_t)B * RIRLEN + b] = __builtin_fmaf(
            __builtin_sqrtf(dx * dx + dy * dy + dz * dz), SR_OVER_C, 40.0f);
    }
    __syncthreads();

    const float rx = s_par[0], ry = s_par[1], rz = s_par[2];
    const float mx = s_par[3], my = s_par[4], mz = s_par[5];
    const float sx = s_par[6], sy = s_par[7], sz = s_par[8];
    const float lw = s_par[9], l4 = s_par[10], l5 = s_par[11];

    // ---- pass A: histogram of ti0 buckets ----
    for (int idx = tid; idx < NIMG; idx += NT) {
        const int p = c_tab.v[idx];
        const int x = (p & 255) - 15;
        const int y = ((p >> 8) & 255) - 15;
        const int z = ((p >> 16) & 255) - 15;
        const float ix = (x & 1) ? __builtin_fmaf(rx, (float)(x + 1), -sx)
                                 : __builtin_fmaf(rx, (float)x, sx);
        const float iy = (y & 1) ? __builtin_fmaf(ry, (float)(y + 1), -sy)
                                 : __builtin_fmaf(ry, (float)y, sy);
        const float iz = (z & 1) ? __builtin_fmaf(rz, (float)(z + 1), -sz)
                                 : __builtin_fmaf(rz, (float)z, sz);
        const float dx = ix - mx, dy = iy - my, dz = iz - mz;
        const float dist  = __builtin_sqrtf(__builtin_fmaf(dx, dx, __builtin_fmaf(dy, dy, dz * dz)));
        const float delay = dist * SR_OVER_C;
        const int   ti0   = (int)__builtin_ceilf(delay) - 40;
        if (ti0 < RIRLEN) atomicAdd(&s_hist[(ti0 + 64) >> 4], 1);
    }
    __syncthreads();

    // ---- exclusive scan over NB==NT buckets (Hillis-Steele) ----
    s_scan[tid] = s_hist[tid];
    __syncthreads();
    for (int d = 1; d < NB; d <<= 1) {
        int tv = (tid >= d) ? s_scan[tid - d] : 0;
        __syncthreads();
        s_scan[tid] += tv;
        __syncthreads();
    }
    if (tid == 0) s_off[0] = 0;
    s_off[tid + 1] = s_scan[tid];
    __syncthreads();
    offs[b * (NB + 1) + tid] = s_off[tid];
    if (tid == NT - 1) offs[b * (NB + 1) + NB] = s_off[NB];
    s_hist[tid] = s_off[tid];          // reuse as per-bucket cursors
    __syncthreads();

    float4* pb = (float4*)params + (size_t)b * NIMG;

    // ---- pass B: params, scattered into bucket-sorted order ----
    for (int idx = tid; idx < NIMG; idx += NT) {
        const int p = c_tab.v[idx];
        const int x = (p & 255) - 15;
        const int y = ((p >> 8) & 255) - 15;
        const int z = ((p >> 16) & 255) - 15;
        const float ix = (x & 1) ? __builtin_fmaf(rx, (float)(x + 1), -sx)
                                 : __builtin_fmaf(rx, (float)x, sx);
        const float iy = (y & 1) ? __builtin_fmaf(ry, (float)(y + 1), -sy)
                                 : __builtin_fmaf(ry, (float)y, sy);
        const float iz = (z & 1) ? __builtin_fmaf(rz, (float)(z + 1), -sz)
                                 : __builtin_fmaf(rz, (float)z, sz);
        const float dx = ix - mx, dy = iy - my, dz = iz - mz;
        const float dist  = __builtin_sqrtf(__builtin_fmaf(dx, dx, __builtin_fmaf(dy, dy, dz * dz)));
        const float delay = dist * SR_OVER_C;
        const float di    = __builtin_ceilf(delay);
        const int   ti0   = (int)di - 40;
        if (ti0 >= RIRLEN) continue;

        const int ew = iabs(x >> 1) + iabs((x + 1) >> 1) + iabs(y >> 1) + iabs((y + 1) >> 1);
        const float att = __builtin_amdgcn_exp2f(__builtin_fmaf((float)ew, lw,
                              __builtin_fmaf((float)iabs(z >> 1), l4,
                                   (float)iabs((z + 1) >> 1) * l5)));
        const float amp  = att * __builtin_amdgcn_rcpf(dist);
        const float frac = di - delay;                  // in [0,1), exact
        const int   dii  = (int)di;

        const int slot = atomicAdd(&s_hist[(ti0 + 64) >> 4], 1);
        float4* qptr = pb + slot;

        if (frac == 0.0f) {
            // exact-integer delay: single tap amp at t=dii; entry made inert
            if (dii < RIRLEN) unsafeAtomicAdd(&out[(size_t)b * RIRLEN + dii], amp);
            *qptr = make_float4(1.0e9f, 0.0f, 0.0f, 0.0f);
        } else {
            float c1p = amp * __builtin_amdgcn_sinf(0.5f * frac) * INV_PI; // sin(pi*frac)/pi
            if (dii & 1) c1p = -c1p;
            const int   md   = dii - (dii / 80) * 80;        // di mod 80
            const float revd = ((float)md - frac) * 0.0125f; // revolutions
            const float Hp   = 0.5f * c1p;
            const float Cdp  = Hp * __builtin_amdgcn_cosf(revd);
            const float Sdp  = Hp * __builtin_amdgcn_sinf(revd);
            *qptr = make_float4(delay, Hp, Cdp, Sdp);
        }
    }
}

// ============================================================================
// K2: gather, snake-balanced. Item = (b, wv, quarter). Item weight is monotone
// in wv (image density ~ r^2), so rank r = wvr-major ordering is monotone and
// the 4-deep snake {w, 16383-w, 16384+w, 32767-w} balances per-wave work to
// ~±10%. Quarters merge via native f32 atomics on out (memset beforehand).
// ============================================================================
__global__ __launch_bounds__(NT, 6)
void rir_gather(const float* __restrict__ params, const int* __restrict__ offs,
                float* __restrict__ out, int B) {
    const int gw   = blockIdx.x * (NT / 64) + (threadIdx.x >> 6);   // 0..8191
    const int lane = threadIdx.x & 63;
    const int bs     = B * SPLIT;
    const int nitems = bs * NWV;

#define EVAL(A) do {                                                         \
        const float xw = tf - (A).x;                                         \
        const float hp = __builtin_fmaf(cth0, (A).z,                         \
                           __builtin_fmaf(sth0, (A).w, (A).y));              \
        float v = hp * __builtin_amdgcn_rcpf(xw);                            \
        v = (__builtin_fabsf(xw) <= 40.0f) ? v : 0.0f;                       \
        acc += v;                                                            \
    } while (0)

    for (int j = 0; (j << 13) < nitems; ++j) {
        const int r = (j & 1) ? (((j + 1) << 13) - 1 - gw) : ((j << 13) + gw);
        if (r >= nitems) continue;

        const int wvr = r / bs;
        const int rem = r - wvr * bs;
        const int s   = rem / B;
        const int b   = rem - s * B;
        const int wv  = (NWV - 1) - wvr;               // heavy windows = low rank

        const int* ob = offs + b * (NB + 1);
        int bmin = (wv * 64 - 16) >> 4;  if (bmin < 0) bmin = 0;
        int bmax = (wv * 64 + 127) >> 4; if (bmax > NB - 1) bmax = NB - 1;
        const int lo  = ob[bmin];
        const int hi  = ob[bmax + 1];
        const int len = hi - lo;
        if (len <= 0) continue;
        const int q  = (len + SPLIT - 1) >> 2;
        const int q0 = lo + s * q;
        int q1 = q0 + q; if (q1 > hi) q1 = hi;
        if (q0 >= q1) continue;

        const int   t  = wv * 64 + lane;
        const float tf = (float)t;
        const int   m  = t - (t / 80) * 80;             // t mod 80
        const float cth0 = __builtin_amdgcn_cosf((float)m * 0.0125f);
        const float sth0 = __builtin_amdgcn_sinf((float)m * 0.0125f);
        const float sl   = (t & 1) ? -1.0f : 1.0f;

        const float4* pp = (const float4*)params + (size_t)b * NIMG;
        float acc = 0.0f;
        int i = q0;
        for (; i + 4 <= q1; i += 4) {
            const float4 a0 = pp[i], a1 = pp[i + 1], a2 = pp[i + 2], a3 = pp[i + 3];
            EVAL(a0); EVAL(a1); EVAL(a2); EVAL(a3);
        }
        for (; i < q1; ++i) { const float4 a0 = pp[i]; EVAL(a0); }

        const float v = sl * acc;
        if (v != 0.0f) unsafeAtomicAdd(&out[(size_t)b * RIRLEN + t], v);
    }
#undef EVAL
}

// ============================================================================
// Fallback (ws too small): round-2 scatter kernel with global-atomic epilogue.
// ============================================================================
__global__ __launch_bounds__(NT, 8)
void rir_scatter(const float* __restrict__ inp, float* __restrict__ out, int B) {
    const int b     = blockIdx.x / BPB;
    const int chunk = blockIdx.x % BPB;
    const int tid   = threadIdx.x;
    const int lane  = tid & 63;
    const int sub   = lane & 7;
    const int grp   = lane >> 3;
    const int wave  = tid >> 6;

    __shared__ float s_rir[RIRLEN];
    __shared__ float s_par[12];
    __shared__ int   s_list[320];
    __shared__ int   s_cnt;

    for (int t = tid; t < RIRLEN; t += NT) s_rir[t] = 0.0f;
    if (tid == 0) {
        s_cnt = 0;
        const float* ip = inp + b * 12;
        float rx = ip[0], ry = ip[1], rz = ip[2];
        float mx = ip[3] * rx, my = ip[4] * ry, mz = ip[5] * rz;
        float sx = ip[6] * rx, sy = ip[7] * ry, sz = ip[8] * rz;
        float aw = __builtin_fmaf(ip[9],  0.84f, 0.01f);
        float a4 = __builtin_fmaf(ip[10], 0.84f, 0.01f);
        float a5 = __builtin_fmaf(ip[11], 0.84f, 0.01f);
        s_par[0] = rx; s_par[1] = ry; s_par[2] = rz;
        s_par[3] = mx; s_par[4] = my; s_par[5] = mz;
        s_par[6] = sx; s_par[7] = sy; s_par[8] = sz;
        s_par[9]  = 0.5f * __builtin_amdgcn_logf(1.0f - aw);
        s_par[10] = 0.5f * __builtin_amdgcn_logf(1.0f - a4);
        s_par[11] = 0.5f * __builtin_amdgcn_logf(1.0f - a5);
        if (chunk == 0) {
            float dx = mx - sx, dy = my - sy, dz = mz - sz;
            out[(size_t)B * RIRLEN + b] = __builtin_fmaf(
                __builtin_sqrtf(dx * dx + dy * dy + dz * dz), SR_OVER_C, 40.0f);
        }
    }
    __syncthreads();

    const float rx = s_par[0], ry = s_par[1], rz = s_par[2];
    const float mx = s_par[3], my = s_par[4], mz = s_par[5];
    const float sx = s_par[6], sy = s_par[7], sz = s_par[8];
    const float lw = s_par[9], l4 = s_par[10], l5 = s_par[11];

    for (int k = tid; ; k += NT) {
        const int idx = chunk + k * BPB;
        if (idx >= NIMG) break;
        const int p = c_tab.v[idx];
        const int x = (p & 255) - 15;
        const int y = ((p >> 8) & 255) - 15;
        const int z = ((p >> 16) & 255) - 15;
        const float ix = (x & 1) ? __builtin_fmaf(rx, (float)(x + 1), -sx)
                                 : __builtin_fmaf(rx, (float)x, sx);
        const float iy = (y & 1) ? __builtin_fmaf(ry, (float)(y + 1), -sy)
                                 : __builtin_fmaf(ry, (float)y, sy);
        const float iz = (z & 1) ? __builtin_fmaf(rz, (float)(z + 1), -sz)
                                 : __builtin_fmaf(rz, (float)z, sz);
        const float dx = ix - mx, dy = iy - my, dz = iz - mz;
        const float d2 = __builtin_fmaf(dx, dx, __builtin_fmaf(dy, dy, dz * dz));
        if (d2 <= 7380.0f) {
            const int slot = atomicAdd(&s_cnt, 1);
            s_list[slot] = p;
        }
    }
    __syncthreads();
    const int cnt = s_cnt;

    float cj[10], sj[10];
    #pragma unroll
    for (int k = 0; k < 10; ++k) {
        const float rev = (float)(sub + 8 * k - 40) * (1.0f / 80.0f);
        cj[k] = __builtin_amdgcn_cosf(rev);
        sj[k] = __builtin_amdgcn_sinf(rev);
    }
    const float slane = (sub & 1) ? -INV_PI : INV_PI;

    for (int base = wave * 8; base < cnt; base += 32) {
        const int e = base + grp;
        const int p = s_list[e < cnt ? e : cnt - 1];
        const int x = (p & 255) - 15;
        const int y = ((p >> 8) & 255) - 15;
        const int z = ((p >> 16) & 255) - 15;
        const float ix = (x & 1) ? __builtin_fmaf(rx, (float)(x + 1), -sx)
                                 : __builtin_fmaf(rx, (float)x, sx);
        const float iy = (y & 1) ? __builtin_fmaf(ry, (float)(y + 1), -sy)
                                 : __builtin_fmaf(ry, (float)y, sy);
        const float iz = (z & 1) ? __builtin_fmaf(rz, (float)(z + 1), -sz)
                                 : __builtin_fmaf(rz, (float)z, sz);
        const float dx = ix - mx, dy = iy - my, dz = iz - mz;
        const float dist  = __builtin_sqrtf(__builtin_fmaf(dx, dx, __builtin_fmaf(dy, dy, dz * dz)));
        const float delay = dist * SR_OVER_C;
        const float di    = __builtin_ceilf(delay);
        const int   ti0   = (int)di - 40;
        const int ew = iabs(x >> 1) + iabs((x + 1) >> 1) + iabs(y >> 1) + iabs((y + 1) >> 1);
        const float att = __builtin_amdgcn_exp2f(__builtin_fmaf((float)ew, lw,
                              __builtin_fmaf((float)iabs(z >> 1), l4,
                                   (float)iabs((z + 1) >> 1) * l5)));
        float amp = att * __builtin_amdgcn_rcpf(dist);
        if (e >= cnt) amp = 0.0f;
        const float frac = di - delay;
        const float c1  = amp * __builtin_amdgcn_sinf(0.5f * frac) * slane;
        const float ca  = 0.5f * __builtin_amdgcn_cosf(frac * (1.0f / 80.0f));
        const float nsa = -0.5f * __builtin_amdgcn_sinf(frac * (1.0f / 80.0f));
        const float x0 = frac + (float)(sub - 40);
        const int   t0 = ti0 + sub;
        #pragma unroll
        for (int k = 0; k < 10; ++k) {
            const float xv = x0 + (float)(8 * k);
            const float h = __builtin_fmaf(ca, cj[k], __builtin_fmaf(nsa, sj[k], 0.5f));
            float v = c1 * h * __builtin_amdgcn_rcpf(xv);
            v = (xv == 0.0f) ? amp : v;
            const int t = t0 + 8 * k;
            if ((unsigned)t < (unsigned)RIRLEN) atomicAdd(&s_rir[t], v);
        }
    }
    __syncthreads();

    float* orow = out + (size_t)b * RIRLEN;
    for (int t = tid; t < RIRLEN; t += NT) {
        const float v = s_rir[t];
        if (v != 0.0f) atomicAdd(&orow[t], v);
    }
}

extern "C" void kernel_launch(void* const* d_in, const int* in_sizes, int n_in,
                              void* d_out, int out_size, void* d_ws, size_t ws_size,
                              hipStream_t stream) {
    const float* inp = (const float*)d_in[0];
    float* out = (float*)d_out;
    const int B = in_sizes[0] / 12;

    const size_t params_bytes = (size_t)B * NIMG * 4 * sizeof(float);
    const size_t offs_bytes   = (size_t)B * (NB + 1) * sizeof(int);
    const int use_ws = (d_ws != nullptr && ws_size >= params_bytes + offs_bytes) ? 1 : 0;

    if (use_ws) {
        float* params = (float*)d_ws;
        int*   offs   = (int*)((char*)d_ws + params_bytes);
        (void)hipMemsetAsync(d_out, 0, (size_t)out_size * sizeof(float), stream);
        rir_prep  <<<dim3(B),  dim3(NT), 0, stream>>>(inp, out, params, offs, B);
        rir_gather<<<dim3(GW), dim3(NT), 0, stream>>>(params, offs, out, B);
    } else {
        (void)hipMemsetAsync(d_out, 0, (size_t)out_size * sizeof(float), stream);
        rir_scatter<<<dim3(B * BPB), dim3(NT), 0, stream>>>(inp, out, B);
    }
}

// Round 6
// 127.261 us; speedup vs baseline: 2.4796x; 1.0172x over previous
//
#include <hip/hip_runtime.h>

#define NIMG    4991
#define RIRLEN  3968
#define NT      256
#define NB      256          // ti0 buckets: width 16, offset +64 -> bucket=(ti0+64)>>4
#define NWV     62           // output windows of 64 bins (RIRLEN/64)
#define SPLIT   4            // image-range quarters per window
#define GW      2048         // gather grid: 2048 blocks x 4 waves = 8192 waves
#define BPB     16           // fallback scatter blocks per batch
#define INV_PI  0.31830988618379067f
#define SR_OVER_C 46.647230320699704f   // 16000 / 343

// ---- compile-time compact image-source table: all (x,y,z), |x|+|y|+|z| <= 15 ----
struct Tab { int v[NIMG]; };
static constexpr Tab make_tab() {
    Tab t{};
    int k = 0;
    for (int x = -15; x <= 15; ++x)
        for (int y = -15; y <= 15; ++y)
            for (int z = -15; z <= 15; ++z) {
                int ax = x < 0 ? -x : x;
                int ay = y < 0 ? -y : y;
                int az = z < 0 ? -z : z;
                if (ax + ay + az <= 15)
                    t.v[k++] = (x + 15) | ((y + 15) << 8) | ((z + 15) << 16);
            }
    return t;
}
__constant__ Tab c_tab = make_tab();

static __device__ __forceinline__ int iabs(int v) { return v < 0 ? -v : v; }

// ============================================================================
// K1: per-batch prep. Zeroes its output row (replaces the memset dispatch),
// then emits one float4 per image, bucket-sorted by ti0 into ws:
//   {delay, Hp, Cdp, Sdp}
//   c1p = amp * (-1)^di * sin(pi*frac) / pi        (frac = ceil(delay)-delay)
//   Hp  = 0.5*c1p
//   Cdp = 0.5*c1p*cos(2*pi*(di mod 80 - frac)/80), Sdp = 0.5*c1p*sin(...)
// Gather: v(t) = (-1)^t * (Hp + cos_t*Cdp + sin_t*Sdp) / (t - delay).
// frac==0 (exact-integer delay => c1p==0, true value = amp at t=di only) is
// special-cased: direct atomic add into out, inert entry (delay=1e9 -> masked).
// ============================================================================
__global__ __launch_bounds__(NT)
void rir_prep(const float* __restrict__ inp, float* __restrict__ out,
              float* __restrict__ params, int* __restrict__ offs, int B) {
    const int b   = blockIdx.x;
    const int tid = threadIdx.x;

    __shared__ float s_par[12];
    __shared__ int   s_hist[NB];
    __shared__ int   s_scan[NB];
    __shared__ int   s_off[NB + 1];

    // zero this batch's output row (replaces hipMemsetAsync; all atomics into
    // this row happen after in-block barriers / in the later gather kernel)
    {
        float4* orow4 = (float4*)(out + (size_t)b * RIRLEN);
        for (int t = tid; t < RIRLEN / 4; t += NT)
            orow4[t] = make_float4(0.f, 0.f, 0.f, 0.f);
    }

    s_hist[tid] = 0;
    if (tid == 0) {
        const float* ip = inp + b * 12;
        float rx = ip[0], ry = ip[1], rz = ip[2];
        float mx = ip[3] * rx, my = ip[4] * ry, mz = ip[5] * rz;
        float sx = ip[6] * rx, sy = ip[7] * ry, sz = ip[8] * rz;
        float aw = __builtin_fmaf(ip[9],  0.84f, 0.01f);
        float a4 = __builtin_fmaf(ip[10], 0.84f, 0.01f);
        float a5 = __builtin_fmaf(ip[11], 0.84f, 0.01f);
        s_par[0] = rx; s_par[1] = ry; s_par[2] = rz;
        s_par[3] = mx; s_par[4] = my; s_par[5] = mz;
        s_par[6] = sx; s_par[7] = sy; s_par[8] = sz;
        s_par[9]  = 0.5f * __builtin_amdgcn_logf(1.0f - aw);   // log2(tr)
        s_par[10] = 0.5f * __builtin_amdgcn_logf(1.0f - a4);
        s_par[11] = 0.5f * __builtin_amdgcn_logf(1.0f - a5);
        float dx = mx - sx, dy = my - sy, dz = mz - sz;
        out[(size_t)B * RIRLEN + b] = __builtin_fmaf(
            __builtin_sqrtf(dx * dx + dy * dy + dz * dz), SR_OVER_C, 40.0f);
    }
    __syncthreads();

    const float rx = s_par[0], ry = s_par[1], rz = s_par[2];
    const float mx = s_par[3], my = s_par[4], mz = s_par[5];
    const float sx = s_par[6], sy = s_par[7], sz = s_par[8];
    const float lw = s_par[9], l4 = s_par[10], l5 = s_par[11];

    // ---- pass A: histogram of ti0 buckets ----
    for (int idx = tid; idx < NIMG; idx += NT) {
        const int p = c_tab.v[idx];
        const int x = (p & 255) - 15;
        const int y = ((p >> 8) & 255) - 15;
        const int z = ((p >> 16) & 255) - 15;
        const float ix = (x & 1) ? __builtin_fmaf(rx, (float)(x + 1), -sx)
                                 : __builtin_fmaf(rx, (float)x, sx);
        const float iy = (y & 1) ? __builtin_fmaf(ry, (float)(y + 1), -sy)
                                 : __builtin_fmaf(ry, (float)y, sy);
        const float iz = (z & 1) ? __builtin_fmaf(rz, (float)(z + 1), -sz)
                                 : __builtin_fmaf(rz, (float)z, sz);
        const float dx = ix - mx, dy = iy - my, dz = iz - mz;
        const float dist  = __builtin_sqrtf(__builtin_fmaf(dx, dx, __builtin_fmaf(dy, dy, dz * dz)));
        const float delay = dist * SR_OVER_C;
        const int   ti0   = (int)__builtin_ceilf(delay) - 40;
        if (ti0 < RIRLEN) atomicAdd(&s_hist[(ti0 + 64) >> 4], 1);
    }
    __syncthreads();

    // ---- exclusive scan over NB==NT buckets (Hillis-Steele) ----
    s_scan[tid] = s_hist[tid];
    __syncthreads();
    for (int d = 1; d < NB; d <<= 1) {
        int tv = (tid >= d) ? s_scan[tid - d] : 0;
        __syncthreads();
        s_scan[tid] += tv;
        __syncthreads();
    }
    if (tid == 0) s_off[0] = 0;
    s_off[tid + 1] = s_scan[tid];
    __syncthreads();
    offs[b * (NB + 1) + tid] = s_off[tid];
    if (tid == NT - 1) offs[b * (NB + 1) + NB] = s_off[NB];
    s_hist[tid] = s_off[tid];          // reuse as per-bucket cursors
    __syncthreads();

    float4* pb = (float4*)params + (size_t)b * NIMG;

    // ---- pass B: params, scattered into bucket-sorted order ----
    for (int idx = tid; idx < NIMG; idx += NT) {
        const int p = c_tab.v[idx];
        const int x = (p & 255) - 15;
        const int y = ((p >> 8) & 255) - 15;
        const int z = ((p >> 16) & 255) - 15;
        const float ix = (x & 1) ? __builtin_fmaf(rx, (float)(x + 1), -sx)
                                 : __builtin_fmaf(rx, (float)x, sx);
        const float iy = (y & 1) ? __builtin_fmaf(ry, (float)(y + 1), -sy)
                                 : __builtin_fmaf(ry, (float)y, sy);
        const float iz = (z & 1) ? __builtin_fmaf(rz, (float)(z + 1), -sz)
                                 : __builtin_fmaf(rz, (float)z, sz);
        const float dx = ix - mx, dy = iy - my, dz = iz - mz;
        const float dist  = __builtin_sqrtf(__builtin_fmaf(dx, dx, __builtin_fmaf(dy, dy, dz * dz)));
        const float delay = dist * SR_OVER_C;
        const float di    = __builtin_ceilf(delay);
        const int   ti0   = (int)di - 40;
        if (ti0 >= RIRLEN) continue;

        const int ew = iabs(x >> 1) + iabs((x + 1) >> 1) + iabs(y >> 1) + iabs((y + 1) >> 1);
        const float att = __builtin_amdgcn_exp2f(__builtin_fmaf((float)ew, lw,
                              __builtin_fmaf((float)iabs(z >> 1), l4,
                                   (float)iabs((z + 1) >> 1) * l5)));
        const float amp  = att * __builtin_amdgcn_rcpf(dist);
        const float frac = di - delay;                  // in [0,1), exact
        const int   dii  = (int)di;

        const int slot = atomicAdd(&s_hist[(ti0 + 64) >> 4], 1);
        float4* qptr = pb + slot;

        if (frac == 0.0f) {
            // exact-integer delay: single tap amp at t=dii; entry made inert
            if (dii < RIRLEN) unsafeAtomicAdd(&out[(size_t)b * RIRLEN + dii], amp);
            *qptr = make_float4(1.0e9f, 0.0f, 0.0f, 0.0f);
        } else {
            float c1p = amp * __builtin_amdgcn_sinf(0.5f * frac) * INV_PI; // sin(pi*frac)/pi
            if (dii & 1) c1p = -c1p;
            const int   md   = dii - (dii / 80) * 80;        // di mod 80
            const float revd = ((float)md - frac) * 0.0125f; // revolutions
            const float Hp   = 0.5f * c1p;
            const float Cdp  = Hp * __builtin_amdgcn_cosf(revd);
            const float Sdp  = Hp * __builtin_amdgcn_sinf(revd);
            *qptr = make_float4(delay, Hp, Cdp, Sdp);
        }
    }
}

// ============================================================================
// K2: gather, snake-balanced, software-pipelined. Item = (b, wv, quarter).
// Weight monotone in wv => 4-deep snake {w, 16383-w, 16384+w, 32767-w}
// balances per-wave work to ~±10%. Rolling regs c0..c3 + prefetch n0..n3
// keep 8 float4 loads architecturally live (true MLP; R5's flat unroll was
// sunk by the compiler -> VGPR 20, depth ~1). Prefetch over-read past hi is
// harmless: it lands in the offs region of ws and is never evaluated.
// Quarters merge via native f32 atomics on out (rows zeroed by prep).
// ============================================================================
__global__ __launch_bounds__(NT, 8)
void rir_gather(const float* __restrict__ params, const int* __restrict__ offs,
                float* __restrict__ out, int B) {
    const int gw   = blockIdx.x * (NT / 64) + (threadIdx.x >> 6);   // 0..8191
    const int lane = threadIdx.x & 63;
    const int bs     = B * SPLIT;
    const int nitems = bs * NWV;

#define EVAL(A) do {                                                         \
        const float xw = tf - (A).x;                                         \
        const float hp = __builtin_fmaf(cth0, (A).z,                         \
                           __builtin_fmaf(sth0, (A).w, (A).y));              \
        float v = hp * __builtin_amdgcn_rcpf(xw);                            \
        v = (__builtin_fabsf(xw) <= 40.0f) ? v : 0.0f;                       \
        acc += v;                                                            \
    } while (0)

    for (int j = 0; (j << 13) < nitems; ++j) {
        const int r = (j & 1) ? (((j + 1) << 13) - 1 - gw) : ((j << 13) + gw);
        if (r >= nitems) continue;

        const int wvr = r / bs;
        const int rem = r - wvr * bs;
        const int s   = rem / B;
        const int b   = rem - s * B;
        const int wv  = (NWV - 1) - wvr;               // heavy windows = low rank

        const int* ob = offs + b * (NB + 1);
        int bmin = (wv * 64 - 16) >> 4;  if (bmin < 0) bmin = 0;
        int bmax = (wv * 64 + 127) >> 4; if (bmax > NB - 1) bmax = NB - 1;
        const int lo  = ob[bmin];
        const int hi  = ob[bmax + 1];
        const int len = hi - lo;
        if (len <= 0) continue;
        const int q  = (len + SPLIT - 1) >> 2;
        const int q0 = lo + s * q;
        int q1 = q0 + q; if (q1 > hi) q1 = hi;
        if (q0 >= q1) continue;

        const int   t  = wv * 64 + lane;
        const float tf = (float)t;
        const int   m  = t - (t / 80) * 80;             // t mod 80
        const float cth0 = __builtin_amdgcn_cosf((float)m * 0.0125f);
        const float sth0 = __builtin_amdgcn_sinf((float)m * 0.0125f);
        const float sl   = (t & 1) ? -1.0f : 1.0f;

        const float4* pp = (const float4*)params + (size_t)b * NIMG;
        float acc = 0.0f;
        int i = q0;
        if (i + 4 <= q1) {
            // rolling 4 + prefetch 4: 8 loads in flight in steady state
            float4 c0 = pp[i], c1 = pp[i + 1], c2 = pp[i + 2], c3 = pp[i + 3];
            for (; i + 8 <= q1; i += 4) {
                const float4 n0 = pp[i + 4], n1 = pp[i + 5],
                             n2 = pp[i + 6], n3 = pp[i + 7];
                EVAL(c0); EVAL(c1); EVAL(c2); EVAL(c3);
                c0 = n0; c1 = n1; c2 = n2; c3 = n3;
            }
            EVAL(c0); EVAL(c1); EVAL(c2); EVAL(c3);
            i += 4;
        }
        for (; i < q1; ++i) { const float4 a0 = pp[i]; EVAL(a0); }

        const float v = sl * acc;
        if (v != 0.0f) unsafeAtomicAdd(&out[(size_t)b * RIRLEN + t], v);
    }
#undef EVAL
}

// ============================================================================
// Fallback (ws too small): round-2 scatter kernel with global-atomic epilogue.
// ============================================================================
__global__ __launch_bounds__(NT, 8)
void rir_scatter(const float* __restrict__ inp, float* __restrict__ out, int B) {
    const int b     = blockIdx.x / BPB;
    const int chunk = blockIdx.x % BPB;
    const int tid   = threadIdx.x;
    const int lane  = tid & 63;
    const int sub   = lane & 7;
    const int grp   = lane >> 3;
    const int wave  = tid >> 6;

    __shared__ float s_rir[RIRLEN];
    __shared__ float s_par[12];
    __shared__ int   s_list[320];
    __shared__ int   s_cnt;

    for (int t = tid; t < RIRLEN; t += NT) s_rir[t] = 0.0f;
    if (tid == 0) {
        s_cnt = 0;
        const float* ip = inp + b * 12;
        float rx = ip[0], ry = ip[1], rz = ip[2];
        float mx = ip[3] * rx, my = ip[4] * ry, mz = ip[5] * rz;
        float sx = ip[6] * rx, sy = ip[7] * ry, sz = ip[8] * rz;
        float aw = __builtin_fmaf(ip[9],  0.84f, 0.01f);
        float a4 = __builtin_fmaf(ip[10], 0.84f, 0.01f);
        float a5 = __builtin_fmaf(ip[11], 0.84f, 0.01f);
        s_par[0] = rx; s_par[1] = ry; s_par[2] = rz;
        s_par[3] = mx; s_par[4] = my; s_par[5] = mz;
        s_par[6] = sx; s_par[7] = sy; s_par[8] = sz;
        s_par[9]  = 0.5f * __builtin_amdgcn_logf(1.0f - aw);
        s_par[10] = 0.5f * __builtin_amdgcn_logf(1.0f - a4);
        s_par[11] = 0.5f * __builtin_amdgcn_logf(1.0f - a5);
        if (chunk == 0) {
            float dx = mx - sx, dy = my - sy, dz = mz - sz;
            out[(size_t)B * RIRLEN + b] = __builtin_fmaf(
                __builtin_sqrtf(dx * dx + dy * dy + dz * dz), SR_OVER_C, 40.0f);
        }
    }
    __syncthreads();

    const float rx = s_par[0], ry = s_par[1], rz = s_par[2];
    const float mx = s_par[3], my = s_par[4], mz = s_par[5];
    const float sx = s_par[6], sy = s_par[7], sz = s_par[8];
    const float lw = s_par[9], l4 = s_par[10], l5 = s_par[11];

    for (int k = tid; ; k += NT) {
        const int idx = chunk + k * BPB;
        if (idx >= NIMG) break;
        const int p = c_tab.v[idx];
        const int x = (p & 255) - 15;
        const int y = ((p >> 8) & 255) - 15;
        const int z = ((p >> 16) & 255) - 15;
        const float ix = (x & 1) ? __builtin_fmaf(rx, (float)(x + 1), -sx)
                                 : __builtin_fmaf(rx, (float)x, sx);
        const float iy = (y & 1) ? __builtin_fmaf(ry, (float)(y + 1), -sy)
                                 : __builtin_fmaf(ry, (float)y, sy);
        const float iz = (z & 1) ? __builtin_fmaf(rz, (float)(z + 1), -sz)
                                 : __builtin_fmaf(rz, (float)z, sz);
        const float dx = ix - mx, dy = iy - my, dz = iz - mz;
        const float d2 = __builtin_fmaf(dx, dx, __builtin_fmaf(dy, dy, dz * dz));
        if (d2 <= 7380.0f) {
            const int slot = atomicAdd(&s_cnt, 1);
            s_list[slot] = p;
        }
    }
    __syncthreads();
    const int cnt = s_cnt;

    float cj[10], sj[10];
    #pragma unroll
    for (int k = 0; k < 10; ++k) {
        const float rev = (float)(sub + 8 * k - 40) * (1.0f / 80.0f);
        cj[k] = __builtin_amdgcn_cosf(rev);
        sj[k] = __builtin_amdgcn_sinf(rev);
    }
    const float slane = (sub & 1) ? -INV_PI : INV_PI;

    for (int base = wave * 8; base < cnt; base += 32) {
        const int e = base + grp;
        const int p = s_list[e < cnt ? e : cnt - 1];
        const int x = (p & 255) - 15;
        const int y = ((p >> 8) & 255) - 15;
        const int z = ((p >> 16) & 255) - 15;
        const float ix = (x & 1) ? __builtin_fmaf(rx, (float)(x + 1), -sx)
                                 : __builtin_fmaf(rx, (float)x, sx);
        const float iy = (y & 1) ? __builtin_fmaf(ry, (float)(y + 1), -sy)
                                 : __builtin_fmaf(ry, (float)y, sy);
        const float iz = (z & 1) ? __builtin_fmaf(rz, (float)(z + 1), -sz)
                                 : __builtin_fmaf(rz, (float)z, sz);
        const float dx = ix - mx, dy = iy - my, dz = iz - mz;
        const float dist  = __builtin_sqrtf(__builtin_fmaf(dx, dx, __builtin_fmaf(dy, dy, dz * dz)));
        const float delay = dist * SR_OVER_C;
        const float di    = __builtin_ceilf(delay);
        const int   ti0   = (int)di - 40;
        const int ew = iabs(x >> 1) + iabs((x + 1) >> 1) + iabs(y >> 1) + iabs((y + 1) >> 1);
        const float att = __builtin_amdgcn_exp2f(__builtin_fmaf((float)ew, lw,
                              __builtin_fmaf((float)iabs(z >> 1), l4,
                                   (float)iabs((z + 1) >> 1) * l5)));
        float amp = att * __builtin_amdgcn_rcpf(dist);
        if (e >= cnt) amp = 0.0f;
        const float frac = di - delay;
        const float c1  = amp * __builtin_amdgcn_sinf(0.5f * frac) * slane;
        const float ca  = 0.5f * __builtin_amdgcn_cosf(frac * (1.0f / 80.0f));
        const float nsa = -0.5f * __builtin_amdgcn_sinf(frac * (1.0f / 80.0f));
        const float x0 = frac + (float)(sub - 40);
        const int   t0 = ti0 + sub;
        #pragma unroll
        for (int k = 0; k < 10; ++k) {
            const float xv = x0 + (float)(8 * k);
            const float h = __builtin_fmaf(ca, cj[k], __builtin_fmaf(nsa, sj[k], 0.5f));
            float v = c1 * h * __builtin_amdgcn_rcpf(xv);
            v = (xv == 0.0f) ? amp : v;
            const int t = t0 + 8 * k;
            if ((unsigned)t < (unsigned)RIRLEN) atomicAdd(&s_rir[t], v);
        }
    }
    __syncthreads();

    float* orow = out + (size_t)b * RIRLEN;
    for (int t = tid; t < RIRLEN; t += NT) {
        const float v = s_rir[t];
        if (v != 0.0f) atomicAdd(&orow[t], v);
    }
}

extern "C" void kernel_launch(void* const* d_in, const int* in_sizes, int n_in,
                              void* d_out, int out_size, void* d_ws, size_t ws_size,
                              hipStream_t stream) {
    const float* inp = (const float*)d_in[0];
    float* out = (float*)d_out;
    const int B = in_sizes[0] / 12;

    const size_t params_bytes = (size_t)B * NIMG * 4 * sizeof(float);
    const size_t offs_bytes   = (size_t)B * (NB + 1) * sizeof(int);
    const int use_ws = (d_ws != nullptr && ws_size >= params_bytes + offs_bytes) ? 1 : 0;

    if (use_ws) {
        float* params = (float*)d_ws;
        int*   offs   = (int*)((char*)d_ws + params_bytes);
        rir_prep  <<<dim3(B),  dim3(NT), 0, stream>>>(inp, out, params, offs, B);
        rir_gather<<<dim3(GW), dim3(NT), 0, stream>>>(params, offs, out, B);
    } else {
        (void)hipMemsetAsync(d_out, 0, (size_t)out_size * sizeof(float), stream);
        rir_scatter<<<dim3(B * BPB), dim3(NT), 0, stream>>>(inp, out, B);
    }
}